// Round 9
// baseline (413.325 us; speedup 1.0000x reference)
//
#include <hip/hip_runtime.h>

#define HBV_B  1024
#define HBV_NZ 1e-5f
#define BUFSZ  (15 * 64)       // one 15-step chunk buffer (64 lanes)

// ---------------------------------------------------------------------------
// SMT pipeline (R8) + soft-transcendental soil chain (R6) + med3 clamps.
// 128 blocks x 512 threads (8 waves) -> 2 waves/SIMD; roles (wv&3):
//   0: SOIL (critical serial recurrence)  1: ROUTE  2: SNOW  3: idler.
// Calibration (R5/R6/R8): wall = 2000 x soil chain latency. hw v_log/v_exp
// dependent latency ~60 cyc -> hw chain ~295 cyc/step (R8 measured 307).
// Soft poly log2/exp2 have ~54/~42 cyc dependency depth; their +28 instr of
// issue is hidden by SMT co-residency (free in R8 structure). Soft chain
// ~246 cyc -> predict ~216 us steady.
// Phase machine (136 barriers/wave):
//   phase p: snow chunk p (p<=133) | soil chunk p-1 (1<=p<=134)
//            | route chunk p-2 (2<=p<=135).  Buffer parity = chunk&1.
// ---------------------------------------------------------------------------

struct F3 { float x, y, z; };

#define DPP_ADD_ROR(x, ctrl) do {                                              \
    int _r = __builtin_amdgcn_update_dpp(0, __float_as_int(x),                 \
                                         (ctrl), 0xF, 0xF, true);              \
    (x) += __int_as_float(_r);                                                 \
} while (0)

// ---- full-rate VALU log2 (normal x > 0), dep depth ~9 ops -----------------
__device__ __forceinline__ float fast_log2(float x) {
    int   i  = __float_as_int(x);
    int   a  = i - 0x3f3504f3;            // split at sqrt(0.5)
    int   eb = a & (int)0xff800000;       // e << 23
    float m  = __int_as_float(i - eb);    // m in [sqrt(.5), sqrt(2))
    float ef = (float)(eb >> 23);
    float t  = m - 1.0f;                  // t in [-0.2929, 0.4142]
    float t2 = t * t;
    float A  = __builtin_fmaf(-2.4999993993e-1f, t, 3.3333331174e-1f);
    float B  = __builtin_fmaf(-1.6668057665e-1f, t, 2.0000714765e-1f);
    float C  = __builtin_fmaf(-1.2420140846e-1f, t, 1.4249322787e-1f);
    float t4 = t2 * t2;
    float D  = __builtin_fmaf(B, t2, A);
    float E  = __builtin_fmaf(1.1676998740e-1f, t2, C);
    float P  = __builtin_fmaf(E, t4, D);
    float t3 = t * t2;
    float ln = __builtin_fmaf(t3, P, __builtin_fmaf(-0.5f, t2, t));
    return __builtin_fmaf(1.4426950408889634f, ln, ef);
}

// ---- full-rate VALU exp2 (x in [-125, 3]), dep depth ~7 ops ---------------
__device__ __forceinline__ float fast_exp2(float x) {
    float n  = __builtin_rintf(x);
    float f  = x - n;                     // f in [-0.5, 0.5]
    int   ni = (int)n;
    float f2 = f * f;
    float A  = __builtin_fmaf(2.402264791363012e-1f, f, 6.931472028550421e-1f);
    float B  = __builtin_fmaf(9.618437357674640e-3f, f, 5.550332471162809e-2f);
    float C  = __builtin_fmaf(1.535336188319500e-4f, f, 1.339887440266574e-3f);
    float D  = __builtin_fmaf(C, f2, B);
    float E  = __builtin_fmaf(D, f2, A);
    float r  = __builtin_fmaf(f, E, 1.0f);
    return __int_as_float(__float_as_int(r) + (ni << 23));
}

// ---- soil step: R6 soft-trans math + v_med3 clamps (lp pre-clamped >=-118)
#define SOIL_STEP(s, rt_, lp_, qdst) do {                                      \
    float rt   = (rt_);                                                        \
    float lp   = (lp_);                                                        \
    float cpet = lp + nBEloglpfc;                                              \
    float CSLZ = parC * SLZ;                                                   \
    float c1   = __builtin_fmaf(-CSLZ, invFC, 1.0f);                           \
    float SMrt = SM + rt;                                                      \
    /* ---- cross-step critical chain ---- */                                  \
    float lSM = fast_log2(SM);                                                 \
    float esw = __builtin_amdgcn_fmed3f(                                       \
        __builtin_fmaf(parBETA, lSM, nBlogFC), -120.0f, 0.0f);                 \
    float sw  = fast_exp2(esw);                                                \
    float SM1 = __builtin_fmaf(-rt, sw, SMrt);                                 \
    float SM2 = fminf(SM1, parFC);                                             \
    float SM3 = __builtin_fmaf(SM2, c1, CSLZ);                                 \
    float lS3 = fast_log2(SM3);                                                \
    float eef = __builtin_amdgcn_fmed3f(                                       \
        __builtin_fmaf(parBETAET, lS3, cpet), -120.0f, lp);                    \
    float PETef = fast_exp2(eef);                                              \
    SM = fmaxf(SM3 - PETef, HBV_NZ);                                           \
    /* ---- off-chain: SUZ/SLZ/Q ---- */                                       \
    float U_ = __builtin_fmaf(rt, sw, SM1 - SM2);   /* recharge+excess */      \
    float S_ = SUZ + U_;                                                       \
    float P_ = fminf(S_, parPERC);                                             \
    float A_ = S_ - P_;                                                        \
    float B_ = fminf(A_, __builtin_fmaf(K0c, A_, K0UZL));                      \
    SUZ = K1c * B_;                                                            \
    float L_ = SLZ - (SM3 - SM2) + P_;                                         \
    SLZ = K2c * L_;                                                            \
    (qdst)[(s) * 64] = __builtin_fmaf(parK2, L_, A_ - SUZ);                    \
} while (0)

#define SOIL_CHUNK(n, po) do {                                                 \
    const float* rs = &rtS[set][(po)];                                         \
    const float* ls = &lpS[set][(po)];                                         \
    float* qd = &qS[set][(po)];                                                \
    float rr[15], lpv[15];                                                     \
    _Pragma("unroll")                                                          \
    for (int k_ = 0; k_ < (n); ++k_) {                                         \
        rr[k_]  = rs[k_ * 64];                                                 \
        lpv[k_] = ls[k_ * 64];                                                 \
    }                                                                          \
    _Pragma("unroll")                                                          \
    for (int s_ = 0; s_ < (n); ++s_) SOIL_STEP(s_, rr[s_], lpv[s_], qd);       \
} while (0)

// ---- snow: forcing load + forcing-only recurrence -> rt, log2(PET) --------
#define SNOW_PHASE(n, cidx) do {                                               \
    float Pf[15], Tf[15], Ef[15];                                              \
    _Pragma("unroll")                                                          \
    for (int k_ = 0; k_ < (n); ++k_) {                                         \
        F3 f = xb3[(size_t)((cidx) * 15 + k_) * HBV_B];                        \
        Pf[k_] = f.x; Tf[k_] = f.y; Ef[k_] = f.z;                              \
    }                                                                          \
    float* rd = &rtS[set][((cidx) & 1) * BUFSZ + lane];                        \
    float* ld = &lpS[set][((cidx) & 1) * BUFSZ + lane];                        \
    _Pragma("unroll")                                                          \
    for (int s_ = 0; s_ < (n); ++s_) {                                         \
        float Pm = Pf[s_], Tc = Tf[s_];                                        \
        float rain = (Tc >= parTT) ? Pm : 0.0f;                                \
        SNW += Pm - rain;                                                      \
        float melt = fminf(fmaxf(__builtin_fmaf(parCFMAX, Tc, negCT), 0.0f),   \
                           SNW);                                               \
        MLT += melt; SNW -= melt;                                              \
        float rfz = fminf(fmaxf(__builtin_fmaf(-CFRC, Tc, CFRCTT), 0.0f),      \
                          MLT);                                                \
        SNW += rfz; MLT -= rfz;                                                \
        float tosoil = fmaxf(__builtin_fmaf(-parCWH, SNW, MLT), 0.0f);         \
        MLT -= tosoil;                                                         \
        rd[s_ * 64] = rain + tosoil;                                           \
        ld[s_ * 64] = fmaxf(__builtin_amdgcn_logf(Ef[s_]), -118.0f);           \
    }                                                                          \
} while (0)

// ---- route: LDS -> 15-tap FIR ring -> DPP mean over m -> global store -----
#define ROUTE_PHASE(n, cidx) do {                                              \
    const float* qsrc = &qS[set][((cidx) & 1) * BUFSZ + lane];                 \
    float qq[15];                                                              \
    _Pragma("unroll")                                                          \
    for (int k_ = 0; k_ < (n); ++k_) qq[k_] = qsrc[k_ * 64];                   \
    _Pragma("unroll")                                                          \
    for (int s_ = 0; s_ < (n); ++s_) {                                         \
        q[s_] = qq[s_];                                                        \
        float qr = 0.0f;                                                       \
        _Pragma("unroll")                                                      \
        for (int k_ = 0; k_ < 15; ++k_)                                        \
            qr += w[k_] * q[(s_ - k_ + 15) % 15];                              \
        DPP_ADD_ROR(qr, 0x128);                                                \
        DPP_ADD_ROR(qr, 0x124);                                                \
        DPP_ADD_ROR(qr, 0x122);                                                \
        DPP_ADD_ROR(qr, 0x121);                                                \
        if (m == 0) out[(size_t)((cidx) * 15 + s_) * HBV_B + b] = qr;          \
    }                                                                          \
} while (0)

__global__ __launch_bounds__(512, 1)
void hbv_smt_kernel(const float* __restrict__ x_phy,   // (2000, 1024, 3)
                    const float* __restrict__ ps,      // (1024, 288)
                    float* __restrict__ out)           // (2000, 1024)
{
    const int lane = (int)threadIdx.x & 63;
    const int wv   = (int)threadIdx.x >> 6;
    const int set  = wv >> 2;                 // 0: cells +0, 1: cells +512
    const int role = wv & 3;                  // 0 soil, 1 route, 2 snow, 3 idle
    const int b    = blockIdx.x * 4 + (lane >> 4) + set * 512;
    const int m    = lane & 15;

    __shared__ float rtS[2][2 * BUFSZ];   // snow -> soil : rain+tosoil
    __shared__ float lpS[2][2 * BUFSZ];   // snow -> soil : log2(PET) >= -118
    __shared__ float qS [2][2 * BUFSZ];   // soil -> route: Qsim

    const float* __restrict__ pb = ps + (size_t)b * 288;

    if (role == 0) {
        // --------------------------- SOIL ----------------------------------
        const float parBETA   = 1.0f   + pb[ 0*16 + m] * 5.0f;
        const float parFC     = 50.0f  + pb[ 1*16 + m] * 950.0f;
        const float parK0     = 0.05f  + pb[ 2*16 + m] * 0.85f;
        const float parK1     = 0.01f  + pb[ 3*16 + m] * 0.49f;
        const float parK2     = 0.001f + pb[ 4*16 + m] * 0.199f;
        const float parLP     = 0.2f   + pb[ 5*16 + m] * 0.8f;
        const float parPERC   =          pb[ 6*16 + m] * 10.0f;
        const float parUZL    =          pb[ 7*16 + m] * 100.0f;
        const float parBETAET = 0.3f   + pb[12*16 + m] * 4.7f;
        const float parC      =          pb[13*16 + m];
        const float invFC  = 1.0f / parFC;
        const float K0c    = 1.0f - parK0;
        const float K0UZL  = parK0 * parUZL;
        const float K1c    = 1.0f - parK1;
        const float K2c    = 1.0f - parK2;
        const float nBlogFC    = -parBETA   * __builtin_amdgcn_logf(parFC);
        const float nBEloglpfc = -parBETAET * __builtin_amdgcn_logf(parLP * parFC);

        float SM = HBV_NZ, SUZ = HBV_NZ, SLZ = HBV_NZ;

        __syncthreads();                                  // phase 0
#pragma unroll 1
        for (int c = 0; c < 133; ++c) {                   // phases 1..133
            SOIL_CHUNK(15, (c & 1) * BUFSZ + lane);
            __syncthreads();
        }
        SOIL_CHUNK(5, BUFSZ + lane);                      // chunk 133, ph 134
        __syncthreads();
        __syncthreads();                                  // phase 135
        // 136 barriers.
    } else if (role == 2) {
        // --------------------------- SNOW ----------------------------------
        const float parTT    = -2.5f + pb[ 8*16 + m] * 5.0f;
        const float parCFMAX = 0.5f  + pb[ 9*16 + m] * 9.5f;
        const float parCFR   =         pb[10*16 + m] * 0.1f;
        const float parCWH   =         pb[11*16 + m] * 0.2f;
        const float CFRC   = parCFR * parCFMAX;
        const float negCT  = -parCFMAX * parTT;
        const float CFRCTT =  CFRC * parTT;
        float SNW = HBV_NZ, MLT = HBV_NZ;
        const F3* __restrict__ xb3 = (const F3*)x_phy + b;

#pragma unroll 1
        for (int p = 0; p < 133; ++p) {                   // phases 0..132
            SNOW_PHASE(15, p);
            __syncthreads();
        }
        SNOW_PHASE(5, 133);                               // phase 133
        __syncthreads();
        __syncthreads();                                  // phase 134
        __syncthreads();                                  // phase 135
        // 136 barriers.
    } else if (role == 1) {
        // --------------------------- ROUTE ---------------------------------
        const float rout_a = pb[256 + m]      * 2.9f;
        const float rout_b = pb[256 + 16 + m] * 6.5f;
        // w[k] ∝ t_k^(a-1) exp(-t_k/theta); Gamma/theta^a cancels under
        // normalization; pre-scaled by 1/16 for the mean over m.
        const float aa    = fmaxf(rout_a, 0.0f) + 0.1f;
        const float theta = fmaxf(rout_b, 0.0f) + 0.5f;
        const float am1   = aa - 1.0f;
        const float nit   = -1.4426950408889634f / theta;
        float w[15];
        float wsum = 0.0f;
#pragma unroll
        for (int k = 0; k < 15; ++k) {
            float tk = (float)k + 0.5f;
            float e  = am1 * __builtin_amdgcn_logf(tk) + nit * tk;
            w[k] = __builtin_amdgcn_exp2f(e);
            wsum += w[k];
        }
        const float wscale = 1.0f / (16.0f * wsum);
#pragma unroll
        for (int k = 0; k < 15; ++k) w[k] *= wscale;
        float q[15];
#pragma unroll
        for (int k = 0; k < 15; ++k) q[k] = 0.0f;

        __syncthreads();                                  // phase 0
        __syncthreads();                                  // phase 1
#pragma unroll 1
        for (int c = 0; c < 133; ++c) {                   // phases 2..134
            ROUTE_PHASE(15, c);
            __syncthreads();
        }
        ROUTE_PHASE(5, 133);                              // phase 135
        __syncthreads();
        // 136 barriers.
    } else {
        // --------------------------- IDLER ---------------------------------
#pragma unroll 1
        for (int p = 0; p < 136; ++p) __syncthreads();
    }
}

extern "C" void kernel_launch(void* const* d_in, const int* in_sizes, int n_in,
                              void* d_out, int out_size, void* d_ws, size_t ws_size,
                              hipStream_t stream) {
    const float* x_phy = (const float*)d_in[0];   // (2000,1024,3) fp32
    const float* ps    = (const float*)d_in[1];   // (1024,288)    fp32
    float* out         = (float*)d_out;           // (2000,1024)   fp32

    // 128 blocks x 512 threads (8 waves, 2/SIMD). Wall = 2000 x soil chain;
    // chain now all full-rate VALU (soft log2/exp2), issue hidden by SMT.
    hbv_smt_kernel<<<128, 512, 0, stream>>>(x_phy, ps, out);
}

// Round 10
// 310.674 us; speedup vs baseline: 1.3304x; 1.3304x over previous
//
#include <hip/hip_runtime.h>

#define HBV_B  1024
#define HBV_NZ 1e-5f
#define SBUF   (30 * 64)       // one 30-step superchunk buffer (64 lanes)

// ---------------------------------------------------------------------------
// R8 structure (best: 255.8us steady) + two shavings.
// 128 blocks x 512 threads (8 waves, 2/SIMD); roles (wv&3):
//   0: SOIL (critical serial recurrence, hw trans)  1: ROUTE  2: SNOW  3: idle.
// Measured floor model: wall = 2000 x SM-chain latency; chain = 4 hw trans
// (~60 cyc dep latency each) + 9 VALU (~6 cyc) ~ 294 cyc; R8 measured 307.
// This round: (a) sw-clamp moved after exp2 as clamp01 -> folds into
// v_exp_f32's output-clamp modifier (-6 cyc chain); (b) 30-step superchunks
// halve barrier count 136 -> 69 (-~6 cyc/step overhead).
// Phase machine (69 barriers/wave), superchunks sc=0..66 (sc66 = 20 steps):
//   phase p: snow sc p (p<=66) | soil sc p-1 (1<=p<=67) | route sc p-2
//   (2<=p<=68). Buffer parity = sc&1. Sub-blocks of 15 keep FIR ring aligned.
// ---------------------------------------------------------------------------

struct F3 { float x, y, z; };

#define DPP_ADD_ROR(x, ctrl) do {                                              \
    int _r = __builtin_amdgcn_update_dpp(0, __float_as_int(x),                 \
                                         (ctrl), 0xF, 0xF, true);              \
    (x) += __int_as_float(_r);                                                 \
} while (0)

// ---- soil step: R8 math; sw-clamp folded into exp output modifier ---------
#define SOIL_STEP(s, rt_, lp_, qdst) do {                                      \
    float rt   = (rt_);                                                        \
    float lp   = (lp_);                                                        \
    float cpet = lp + nBEloglpfc;                                              \
    float CSLZ = parC * SLZ;                                                   \
    float c1   = __builtin_fmaf(-CSLZ, invFC, 1.0f);                           \
    float SMrt = SM + rt;                                                      \
    /* ---- cross-step critical chain ---- */                                  \
    float lSM = __builtin_amdgcn_logf(SM);                                     \
    float esw = __builtin_fmaf(parBETA, lSM, nBlogFC);                         \
    float swr = __builtin_amdgcn_exp2f(esw);                                   \
    float sw  = fminf(fmaxf(swr, 0.0f), 1.0f);   /* clamp01 -> v_exp clamp */  \
    float SM1 = __builtin_fmaf(-rt, sw, SMrt);                                 \
    float SM2 = fminf(SM1, parFC);                                             \
    float SM3 = __builtin_fmaf(SM2, c1, CSLZ);                                 \
    float lS3 = __builtin_amdgcn_logf(SM3);                                    \
    float eef = fminf(__builtin_fmaf(parBETAET, lS3, cpet), lp);               \
    float PETef = __builtin_amdgcn_exp2f(eef);                                 \
    SM = fmaxf(SM3 - PETef, HBV_NZ);                                           \
    /* ---- off-chain: SUZ/SLZ/Q ---- */                                       \
    float U_ = __builtin_fmaf(rt, sw, SM1 - SM2);   /* recharge+excess */      \
    float S_ = SUZ + U_;                                                       \
    float P_ = fminf(S_, parPERC);                                             \
    float A_ = S_ - P_;                                                        \
    float B_ = fminf(A_, __builtin_fmaf(K0c, A_, K0UZL));                      \
    SUZ = K1c * B_;                                                            \
    float L_ = SLZ - (SM3 - SM2) + P_;                                         \
    SLZ = K2c * L_;                                                            \
    (qdst)[(s) * 64] = __builtin_fmaf(parK2, L_, A_ - SUZ);                    \
} while (0)

// One 15-or-5-step sub-block: stage LDS -> registers, run steps.
#define SOIL_HALF(nn, ofs) do {                                                \
    const float* rs = &rtS[set][(ofs)];                                        \
    const float* ls = &lpS[set][(ofs)];                                        \
    float* qd = &qS[set][(ofs)];                                               \
    float rr[15], lpv[15];                                                     \
    _Pragma("unroll")                                                          \
    for (int k_ = 0; k_ < (nn); ++k_) {                                        \
        rr[k_]  = rs[k_ * 64];                                                 \
        lpv[k_] = ls[k_ * 64];                                                 \
    }                                                                          \
    _Pragma("unroll")                                                          \
    for (int s_ = 0; s_ < (nn); ++s_) SOIL_STEP(s_, rr[s_], lpv[s_], qd);      \
} while (0)

// ---- snow: forcing load + forcing-only recurrence -> rt, log2(PET) --------
#define SNOW_HALF(nn, tb, ofs) do {                                            \
    float Pf[15], Tf[15], Ef[15];                                              \
    _Pragma("unroll")                                                          \
    for (int k_ = 0; k_ < (nn); ++k_) {                                        \
        F3 f = xb3[(size_t)((tb) + k_) * HBV_B];                               \
        Pf[k_] = f.x; Tf[k_] = f.y; Ef[k_] = f.z;                              \
    }                                                                          \
    float* rd = &rtS[set][(ofs)];                                              \
    float* ld = &lpS[set][(ofs)];                                              \
    _Pragma("unroll")                                                          \
    for (int s_ = 0; s_ < (nn); ++s_) {                                        \
        float Pm = Pf[s_], Tc = Tf[s_];                                        \
        float rain = (Tc >= parTT) ? Pm : 0.0f;                                \
        SNW += Pm - rain;                                                      \
        float melt = fminf(fmaxf(__builtin_fmaf(parCFMAX, Tc, negCT), 0.0f),   \
                           SNW);                                               \
        MLT += melt; SNW -= melt;                                              \
        float rfz = fminf(fmaxf(__builtin_fmaf(-CFRC, Tc, CFRCTT), 0.0f),      \
                          MLT);                                                \
        SNW += rfz; MLT -= rfz;                                                \
        float tosoil = fmaxf(__builtin_fmaf(-parCWH, SNW, MLT), 0.0f);         \
        MLT -= tosoil;                                                         \
        rd[s_ * 64] = rain + tosoil;                                           \
        ld[s_ * 64] = __builtin_amdgcn_logf(Ef[s_]);                           \
    }                                                                          \
} while (0)

// ---- route: LDS -> 15-tap FIR ring -> DPP mean over m -> store ------------
// (tb) is always a multiple of 15, so ring slot == local index s_.
#define ROUTE_HALF(nn, tb, ofs) do {                                           \
    const float* qsrc = &qS[set][(ofs)];                                       \
    float qq[15];                                                              \
    _Pragma("unroll")                                                          \
    for (int k_ = 0; k_ < (nn); ++k_) qq[k_] = qsrc[k_ * 64];                  \
    _Pragma("unroll")                                                          \
    for (int s_ = 0; s_ < (nn); ++s_) {                                        \
        q[s_] = qq[s_];                                                        \
        float qr = 0.0f;                                                       \
        _Pragma("unroll")                                                      \
        for (int k_ = 0; k_ < 15; ++k_)                                        \
            qr += w[k_] * q[(s_ - k_ + 15) % 15];                              \
        DPP_ADD_ROR(qr, 0x128);                                                \
        DPP_ADD_ROR(qr, 0x124);                                                \
        DPP_ADD_ROR(qr, 0x122);                                                \
        DPP_ADD_ROR(qr, 0x121);                                                \
        if (m == 0) out[(size_t)((tb) + s_) * HBV_B + b] = qr;                 \
    }                                                                          \
} while (0)

__global__ __launch_bounds__(512, 1)
void hbv_smt_kernel(const float* __restrict__ x_phy,   // (2000, 1024, 3)
                    const float* __restrict__ ps,      // (1024, 288)
                    float* __restrict__ out)           // (2000, 1024)
{
    const int lane = (int)threadIdx.x & 63;
    const int wv   = (int)threadIdx.x >> 6;
    const int set  = wv >> 2;                 // 0: cells +0, 1: cells +512
    const int role = wv & 3;                  // 0 soil, 1 route, 2 snow, 3 idle
    const int b    = blockIdx.x * 4 + (lane >> 4) + set * 512;
    const int m    = lane & 15;

    __shared__ float rtS[2][2 * SBUF];   // snow -> soil : rain+tosoil
    __shared__ float lpS[2][2 * SBUF];   // snow -> soil : log2(PET)
    __shared__ float qS [2][2 * SBUF];   // soil -> route: Qsim

    const float* __restrict__ pb = ps + (size_t)b * 288;

    if (role == 0) {
        // --------------------------- SOIL ----------------------------------
        const float parBETA   = 1.0f   + pb[ 0*16 + m] * 5.0f;
        const float parFC     = 50.0f  + pb[ 1*16 + m] * 950.0f;
        const float parK0     = 0.05f  + pb[ 2*16 + m] * 0.85f;
        const float parK1     = 0.01f  + pb[ 3*16 + m] * 0.49f;
        const float parK2     = 0.001f + pb[ 4*16 + m] * 0.199f;
        const float parLP     = 0.2f   + pb[ 5*16 + m] * 0.8f;
        const float parPERC   =          pb[ 6*16 + m] * 10.0f;
        const float parUZL    =          pb[ 7*16 + m] * 100.0f;
        const float parBETAET = 0.3f   + pb[12*16 + m] * 4.7f;
        const float parC      =          pb[13*16 + m];
        const float invFC  = 1.0f / parFC;
        const float K0c    = 1.0f - parK0;
        const float K0UZL  = parK0 * parUZL;
        const float K1c    = 1.0f - parK1;
        const float K2c    = 1.0f - parK2;
        const float nBlogFC    = -parBETA   * __builtin_amdgcn_logf(parFC);
        const float nBEloglpfc = -parBETAET * __builtin_amdgcn_logf(parLP * parFC);

        float SM = HBV_NZ, SUZ = HBV_NZ, SLZ = HBV_NZ;

        __syncthreads();                                  // phase 0
#pragma unroll 1
        for (int sc = 0; sc < 66; ++sc) {                 // phases 1..66
            const int po = (sc & 1) * SBUF + lane;
            SOIL_HALF(15, po);
            SOIL_HALF(15, po + 15 * 64);
            __syncthreads();
        }
        // sc=66 (20 steps, parity 0): phase 67
        SOIL_HALF(15, lane);
        SOIL_HALF(5, lane + 15 * 64);
        __syncthreads();
        __syncthreads();                                  // phase 68
        // 69 barriers.
    } else if (role == 2) {
        // --------------------------- SNOW ----------------------------------
        const float parTT    = -2.5f + pb[ 8*16 + m] * 5.0f;
        const float parCFMAX = 0.5f  + pb[ 9*16 + m] * 9.5f;
        const float parCFR   =         pb[10*16 + m] * 0.1f;
        const float parCWH   =         pb[11*16 + m] * 0.2f;
        const float CFRC   = parCFR * parCFMAX;
        const float negCT  = -parCFMAX * parTT;
        const float CFRCTT =  CFRC * parTT;
        float SNW = HBV_NZ, MLT = HBV_NZ;
        const F3* __restrict__ xb3 = (const F3*)x_phy + b;

#pragma unroll 1
        for (int sc = 0; sc < 66; ++sc) {                 // phases 0..65
            const int po = (sc & 1) * SBUF + lane;
            SNOW_HALF(15, sc * 30,      po);
            SNOW_HALF(15, sc * 30 + 15, po + 15 * 64);
            __syncthreads();
        }
        // sc=66: phase 66
        SNOW_HALF(15, 1980, lane);
        SNOW_HALF(5, 1995, lane + 15 * 64);
        __syncthreads();
        __syncthreads();                                  // phase 67
        __syncthreads();                                  // phase 68
        // 69 barriers.
    } else if (role == 1) {
        // --------------------------- ROUTE ---------------------------------
        const float rout_a = pb[256 + m]      * 2.9f;
        const float rout_b = pb[256 + 16 + m] * 6.5f;
        // w[k] ∝ t_k^(a-1) exp(-t_k/theta); Gamma/theta^a cancels under
        // normalization; pre-scaled by 1/16 for the mean over m.
        const float aa    = fmaxf(rout_a, 0.0f) + 0.1f;
        const float theta = fmaxf(rout_b, 0.0f) + 0.5f;
        const float am1   = aa - 1.0f;
        const float nit   = -1.4426950408889634f / theta;
        float w[15];
        float wsum = 0.0f;
#pragma unroll
        for (int k = 0; k < 15; ++k) {
            float tk = (float)k + 0.5f;
            float e  = am1 * __builtin_amdgcn_logf(tk) + nit * tk;
            w[k] = __builtin_amdgcn_exp2f(e);
            wsum += w[k];
        }
        const float wscale = 1.0f / (16.0f * wsum);
#pragma unroll
        for (int k = 0; k < 15; ++k) w[k] *= wscale;
        float q[15];
#pragma unroll
        for (int k = 0; k < 15; ++k) q[k] = 0.0f;

        __syncthreads();                                  // phase 0
        __syncthreads();                                  // phase 1
#pragma unroll 1
        for (int sc = 0; sc < 66; ++sc) {                 // phases 2..67
            const int po = (sc & 1) * SBUF + lane;
            ROUTE_HALF(15, sc * 30,      po);
            ROUTE_HALF(15, sc * 30 + 15, po + 15 * 64);
            __syncthreads();
        }
        // sc=66: phase 68
        ROUTE_HALF(15, 1980, lane);
        ROUTE_HALF(5, 1995, lane + 15 * 64);
        __syncthreads();
        // 69 barriers.
    } else {
        // --------------------------- IDLER ---------------------------------
#pragma unroll 1
        for (int p = 0; p < 69; ++p) __syncthreads();
    }
}

extern "C" void kernel_launch(void* const* d_in, const int* in_sizes, int n_in,
                              void* d_out, int out_size, void* d_ws, size_t ws_size,
                              hipStream_t stream) {
    const float* x_phy = (const float*)d_in[0];   // (2000,1024,3) fp32
    const float* ps    = (const float*)d_in[1];   // (1024,288)    fp32
    float* out         = (float*)d_out;           // (2000,1024)   fp32

    // 128 blocks x 512 threads (8 waves, 2/SIMD). Wall = 2000 x soil chain
    // (4 hw trans + 9 VALU ~ 288 cyc after clamp fold); barriers halved.
    hbv_smt_kernel<<<128, 512, 0, stream>>>(x_phy, ps, out);
}